// Round 8
// baseline (3897.909 us; speedup 1.0000x reference)
//
#include <hip/hip_runtime.h>

#define K_DIM 512
#define S_DIM 64
#define T_LEN 64
#define GCUS  8       // CUs per group (K split 8 ways, 64 rows each)
#define BW    16      // sequences per group
#define NGRP  32      // 32 groups x 16 seqs = 512 sequences
#define NWG   (NGRP*GCUS)   // 256 workgroups = 256 CUs
#define KSL   64      // k-slice width per CU
#define AP    (K_DIM+8)  // padded row (1040B stride: conflict-uniform for b128, 16B-aligned)
#define CP    80      // Cl padded row (160B stride)

typedef float f32x4 __attribute__((ext_vector_type(4)));
typedef short bf16x8 __attribute__((ext_vector_type(8)));

__device__ __forceinline__ short f2bf(float f) {
    unsigned u = __builtin_bit_cast(unsigned, f);
    u += 0x7fffu + ((u >> 16) & 1u);   // round-to-nearest-even
    return (short)(u >> 16);
}

// ---------------- pre-pass: build bf16/derived operands in workspace ----------------
__global__ void ssm_prep(const float* __restrict__ A, const float* __restrict__ B,
                         const float* __restrict__ C, const float* __restrict__ Pp,
                         short* __restrict__ A16, short* __restrict__ Ceff16,
                         float* __restrict__ PI32, float* __restrict__ PB32) {
    int i = blockIdx.x * blockDim.x + threadIdx.x;
    int stride = gridDim.x * blockDim.x;
    for (int idx = i; idx < K_DIM * K_DIM; idx += stride)
        A16[idx] = f2bf(A[idx]);
    for (int idx = i; idx < S_DIM * K_DIM; idx += stride) {
        int s = idx >> 9;               // K_DIM == 512
        int k = idx & (K_DIM - 1);
        float p = 1.0f / (1.0f + expf(-Pp[idx]));
        PI32[idx]   = p;
        Ceff16[idx] = f2bf(C[idx] * p);
        PB32[idx]   = p * B[k * S_DIM + s];   // pi[s][k] * B[k][s]
    }
}

#define MFMA_(xa, fb, acc) acc = __builtin_amdgcn_mfma_f32_16x16x32_bf16(xa, fb, acc, 0, 0, 0)

// ---------------- main: systolic 8-CU groups, A LDS-resident, 256 WGs x 256 thr ----------------
__global__ __launch_bounds__(256) void ssm_sys(
    const short* __restrict__ A16,     // [K][K] bf16 row-major
    const short* __restrict__ Ceff16,  // [S][K] bf16
    const float* __restrict__ PI32,    // [S][K]
    const float* __restrict__ PB32,    // [S][K]
    const float* __restrict__ init,    // [K]
    const int*   __restrict__ tokens,  // [BSZ][T]
    short*       __restrict__ xbuf,    // [NGRP][GCUS][2][BW][KSL] bf16 exchange
    float*       __restrict__ lgbuf,   // [NGRP][GCUS][2][BW][S]   logits partials
    int*         __restrict__ flags,   // [NGRP][GCUS] monotone step counters
    float*       __restrict__ out)     // [BSZ]
{
    __shared__ short Al[KSL][AP];      // 66.6 KB this CU's 64 A-rows (step-invariant!)
    __shared__ short Xf[BW][AP];       // 16.6 KB full x (bf16) for the group's 16 seqs
    __shared__ short Cl[S_DIM][CP];    // 10.2 KB Ceff k-slice [64 s][64 k]
    __shared__ int   tokS[BW][T_LEN];  //  4.1 KB  (total ~97.5 KB -> 1 WG/CU)

    const int tid = threadIdx.x;
    const int w  = tid >> 6;     // wave 0..3, owns k_local [w*16, w*16+16)
    const int l  = tid & 63;
    const int lg = l >> 4;
    const int lr = l & 15;
    const int bid = blockIdx.x;
    const int g = bid >> 3;      // group 0..31
    const int c = bid & 7;       // member 0..7
    const int kbase = c * KSL;   // global k of this CU's slice
    const int b0 = g * BW;

    // ---- one-time staging ----
    for (int idx = tid; idx < BW * T_LEN; idx += 256) {
        int r = idx >> 6, t = idx & 63;
        tokS[r][t] = tokens[(b0 + r) * T_LEN + t];
    }
    for (int idx = tid; idx < BW * K_DIM; idx += 256) {
        int r = idx >> 9, k = idx & (K_DIM - 1);
        Xf[r][k] = f2bf(init[k]);
    }
    for (int q = tid; q < (S_DIM * KSL) / 8; q += 256) {       // 512 chunks
        int s = q >> 3, k8 = (q & 7) * 8;
        *(bf16x8*)&Cl[s][k8] = *(const bf16x8*)(Ceff16 + s * K_DIM + kbase + k8);
    }
    for (int q = tid; q < (KSL * K_DIM) / 8; q += 256) {       // 4096 chunks
        int r = q >> 6, k8 = (q & 63) * 8;
        *(bf16x8*)&Al[r][k8] = *(const bf16x8*)(A16 + (kbase + r) * K_DIM + k8);
    }

    // fp32 master state: xm[e] = x[seq=4*lg+e][k = kbase + w*16 + lr]
    const int kl  = w * 16 + lr;
    const int kgl = kbase + kl;
    float xm[4];
    {
        float iv = init[kgl];
        #pragma unroll
        for (int e = 0; e < 4; ++e) xm[e] = iv;
    }
    float llacc = 0.0f;
    int* fl = flags + g * GCUS;
    __syncthreads();

    for (int t = 0; t < T_LEN; ++t) {
        const int par = t & 1;

        // ---- P1: logits partial over this CU's 64-k slice (wave w = s-tile w)
        f32x4 lga = {0.f, 0.f, 0.f, 0.f};
        {
            bf16x8 xa0 = *(const bf16x8*)&Xf[lr][kbase + 8 * lg];
            bf16x8 cb0 = *(const bf16x8*)&Cl[w * 16 + lr][8 * lg];
            MFMA_(xa0, cb0, lga);
            bf16x8 xa1 = *(const bf16x8*)&Xf[lr][kbase + 32 + 8 * lg];
            bf16x8 cb1 = *(const bf16x8*)&Cl[w * 16 + lr][32 + 8 * lg];
            MFMA_(xa1, cb1, lga);
        }
        float* lgb = lgbuf + (((g * GCUS + c) * 2 + par) * BW) * S_DIM;
        #pragma unroll
        for (int e = 0; e < 4; ++e)
            lgb[(4 * lg + e) * S_DIM + w * 16 + lr] = lga[e];

        // ---- P2: update GEMM: acc = sum_j x[seq][j] * A[kgl][j], A from LDS
        f32x4 acc = {0.f, 0.f, 0.f, 0.f};
        #pragma unroll
        for (int s = 0; s < 16; ++s) {
            bf16x8 xa = *(const bf16x8*)&Xf[lr][s * 32 + 8 * lg];
            bf16x8 ab = *(const bf16x8*)&Al[kl][s * 32 + 8 * lg];
            MFMA_(xa, ab, acc);
        }

        // ---- P3: gating (fp32 master), publish bf16 slice
        short* xb = xbuf + (((g * GCUS + c) * 2 + par) * BW) * KSL;
        int mytok[4];
        #pragma unroll
        for (int e = 0; e < 4; ++e) mytok[e] = tokS[4 * lg + e][t];
        #pragma unroll
        for (int e = 0; e < 4; ++e) {
            float p  = PI32[mytok[e] * K_DIM + kgl];
            float pb = PB32[mytok[e] * K_DIM + kgl];
            float nx = xm[e] + p * (acc[e] - xm[e]) + pb;
            xm[e] = nx;
            xb[(4 * lg + e) * KSL + kl] = f2bf(nx);
        }

        __syncthreads();            // all publish stores drained (vmcnt 0 at barrier)
        __threadfence();            // agent release: L2 writeback
        if (tid == 0)
            __hip_atomic_store(fl + c, t + 1, __ATOMIC_RELEASE, __HIP_MEMORY_SCOPE_AGENT);
        if (tid < GCUS) {           // lanes 0..7 of wave 0 spin on the 8 member flags
            while (__hip_atomic_load(fl + tid, __ATOMIC_RELAXED, __HIP_MEMORY_SCOPE_AGENT) < t + 1) {}
        }
        __syncthreads();
        __threadfence();            // agent acquire: invalidate stale L2 lines

        // ---- duty softmax (waves 0,1: seqs 2c, 2c+1) || Xf rebuild (waves 2,3)
        if (w < 2) {
            int seq = 2 * c + w;
            float v = 0.f;
            #pragma unroll
            for (int c2 = 0; c2 < GCUS; ++c2)
                v += lgbuf[((((g * GCUS + c2) * 2 + par) * BW) + seq) * S_DIM + l];
            float m = v;
            #pragma unroll
            for (int d = 1; d < 64; d <<= 1) m = fmaxf(m, __shfl_xor(m, d));
            float ex = expf(v - m), sum = ex;
            #pragma unroll
            for (int d = 1; d < 64; d <<= 1) sum += __shfl_xor(sum, d);
            int tok = tokS[seq][t];
            float sel = (l == tok) ? v : 0.f;
            #pragma unroll
            for (int d = 1; d < 64; d <<= 1) sel += __shfl_xor(sel, d);
            llacc += sel - m - logf(sum);
        } else {
            int q = tid - 128;      // 0..127: seq = q>>3, 8-elem chunk (q&7)
            #pragma unroll
            for (int c2 = 0; c2 < GCUS; ++c2) {
                const short* src = xbuf + (((g * GCUS + c2) * 2 + par) * BW) * KSL;
                bf16x8 vv = *(const bf16x8*)(src + (q >> 3) * KSL + (q & 7) * 8);
                *(bf16x8*)&Xf[q >> 3][c2 * KSL + (q & 7) * 8] = vv;
            }
        }
        __syncthreads();            // new Xf visible to all waves
    }

    if (w < 2 && l == 0)
        out[b0 + 2 * c + w] = llacc;
}

extern "C" void kernel_launch(void* const* d_in, const int* in_sizes, int n_in,
                              void* d_out, int out_size, void* d_ws, size_t ws_size,
                              hipStream_t stream) {
    const float* A  = (const float*)d_in[0];   // (512,512)
    const float* B  = (const float*)d_in[1];   // (512,64)
    const float* C  = (const float*)d_in[2];   // (64,512)
    const float* Pp = (const float*)d_in[3];   // (64,512)
    const float* init = (const float*)d_in[4]; // (512,)
    const int* tokens = (const int*)d_in[5];   // (512,64)
    float* out = (float*)d_out;

    // workspace layout (total ~3.82 MB)
    short* A16    = (short*)d_ws;                              // 524288 B @ 0
    short* Ceff16 = (short*)((char*)d_ws + 524288);            //  65536 B
    float* PI32   = (float*)((char*)d_ws + 589824);            // 131072 B
    float* PB32   = (float*)((char*)d_ws + 720896);            // 131072 B
    short* xbuf   = (short*)((char*)d_ws + 851968);            // 32*8*2*16*64*2 = 1048576 B
    float* lgbuf  = (float*)((char*)d_ws + 1900544);           // 32*8*2*16*64*4 = 2097152 B
    int*   flags  = (int*)  ((char*)d_ws + 3997696);           // 1024 B

    ssm_prep<<<256, 256, 0, stream>>>(A, B, C, Pp, A16, Ceff16, PI32, PB32);
    hipMemsetAsync(flags, 0, NGRP * GCUS * sizeof(int), stream);

    void* args[] = { (void*)&A16, (void*)&Ceff16, (void*)&PI32, (void*)&PB32,
                     (void*)&init, (void*)&tokens, (void*)&xbuf, (void*)&lgbuf,
                     (void*)&flags, (void*)&out };
    if (hipLaunchCooperativeKernel((void*)ssm_sys, dim3(NWG), dim3(256),
                                   args, 0, stream) != hipSuccess) {
        // fallback: 256 WGs at 1 WG/CU on 256 CUs are de-facto co-resident
        ssm_sys<<<NWG, 256, 0, stream>>>(A16, Ceff16, PI32, PB32, init, tokens,
                                         xbuf, lgbuf, flags, out);
    }
}

// Round 9
// 1008.291 us; speedup vs baseline: 3.8659x; 3.8659x over previous
//
#include <hip/hip_runtime.h>

#define K_DIM 512
#define S_DIM 64
#define T_LEN 64
#define BW    16      // sequences per workgroup
#define NWG   32      // 32 workgroups x 16 seqs = 512

typedef float f32x4 __attribute__((ext_vector_type(4)));
typedef short bf16x8 __attribute__((ext_vector_type(8)));

__device__ __forceinline__ short f2bf(float f) {
    unsigned u = __builtin_bit_cast(unsigned, f);
    u += 0x7fffu + ((u >> 16) & 1u);   // round-to-nearest-even
    return (short)(u >> 16);
}

// ---------------- pre-pass: build bf16/derived operands in workspace ----------------
__global__ void ssm_prep(const float* __restrict__ A, const float* __restrict__ B,
                         const float* __restrict__ C, const float* __restrict__ Pp,
                         short* __restrict__ A16, short* __restrict__ Ceff16,
                         float* __restrict__ PI32, float* __restrict__ PB32) {
    int i = blockIdx.x * blockDim.x + threadIdx.x;
    int stride = gridDim.x * blockDim.x;
    for (int idx = i; idx < K_DIM * K_DIM; idx += stride)
        A16[idx] = f2bf(A[idx]);
    for (int idx = i; idx < S_DIM * K_DIM; idx += stride) {
        int s = idx >> 9;               // K_DIM == 512
        int k = idx & (K_DIM - 1);
        float p = 1.0f / (1.0f + expf(-Pp[idx]));
        PI32[idx]   = p;
        Ceff16[idx] = f2bf(C[idx] * p);
        PB32[idx]   = p * B[k * S_DIM + s];   // pi[s][k] * B[k][s]
    }
}

#define MFMA_(xa, fb, acc) acc = __builtin_amdgcn_mfma_f32_16x16x32_bf16(xa, fb, acc, 0, 0, 0)

// direct global->LDS DMA, 16B/lane, zero VGPR cost
#define GLD(src, dst) __builtin_amdgcn_global_load_lds( \
    (const __attribute__((address_space(1))) void*)(src), \
    (__attribute__((address_space(3))) void*)(dst), 16, 0, 0)

// issue slice Gn's 4 nt-fragment blocks into ring buffer (Gn&3)
#define ISSUE(Gn) do { \
    GLD(aP0 + (Gn) * 32, &Aring[w][(Gn) & 3][0][0]); \
    GLD(aP1 + (Gn) * 32, &Aring[w][(Gn) & 3][1][0]); \
    GLD(aP2 + (Gn) * 32, &Aring[w][(Gn) & 3][2][0]); \
    GLD(aP3 + (Gn) * 32, &Aring[w][(Gn) & 3][3][0]); \
} while (0)

// counted wait: 12 newest loads (3 slices ahead) may stay in flight
#define WAITV asm volatile("s_waitcnt vmcnt(12)" ::: "memory")

// raw barrier: drain LDS ops only; vmem pipeline survives across it
#define LBAR  asm volatile("s_waitcnt lgkmcnt(0)\ns_barrier" ::: "memory")

// consume slice G: 1 Xb frag + 4 ring frags (lane l reads back its own 16B) + 4 MFMA
#define CONS(G) do { \
    bf16x8 xa = *(const bf16x8*)&Xb[lr][(G) * 32 + 8 * lg]; \
    bf16x8 f0 = *(const bf16x8*)&Aring[w][(G) & 3][0][l * 8]; \
    bf16x8 f1 = *(const bf16x8*)&Aring[w][(G) & 3][1][l * 8]; \
    bf16x8 f2 = *(const bf16x8*)&Aring[w][(G) & 3][2][l * 8]; \
    bf16x8 f3 = *(const bf16x8*)&Aring[w][(G) & 3][3][l * 8]; \
    MFMA_(xa, f0, acc0); MFMA_(xa, f1, acc1); \
    MFMA_(xa, f2, acc2); MFMA_(xa, f3, acc3); \
} while (0)

// ---------------- main: 32 WGs x 512 threads (8 waves), 16 seqs/WG, 64 steps ----------------
__global__ __launch_bounds__(512) void ssm_main(
    const short* __restrict__ A16,     // [K][K] bf16 row-major
    const short* __restrict__ Ceff16,  // [S][K] bf16
    const float* __restrict__ PI32,    // [S][K]
    const float* __restrict__ PB32,    // [S][K]
    const float* __restrict__ init,    // [K]
    const int*   __restrict__ tokens,  // [BSZ][T]
    float*       __restrict__ out)     // [BSZ]
{
    __shared__ short Aring[8][4][4][512];   // 128 KB: per-wave 4-deep slice ring (DMA dest)
    __shared__ short Xb[BW][520];           // 16.6 KB bf16 state
    __shared__ float Lg[2][BW][68];         //  8.7 KB logits partials (2 K-halves)
    __shared__ int   tokS[BW][T_LEN];       //  4.1 KB   (total 160,512 B -> 1 WG/CU)

    const int tid = threadIdx.x;
    const int w  = tid >> 6;     // wave 0..7, owns k-range [w*64, w*64+64)
    const int l  = tid & 63;
    const int lg = l >> 4;
    const int lr = l & 15;
    const int b0 = blockIdx.x * BW;

    for (int idx = tid; idx < BW * T_LEN; idx += 512) {
        int r = idx >> 6, t = idx & 63;
        tokS[r][t] = tokens[(b0 + r) * T_LEN + t];
    }
    for (int idx = tid; idx < BW * K_DIM; idx += 512) {
        int r = idx >> 9, k = idx & (K_DIM - 1);
        Xb[r][k] = f2bf(init[k]);
    }
    // fp32 master state: xm[nt][e] = x[seq=4*lg+e][k = w*64 + nt*16 + lr]
    float xm[4][4];
    #pragma unroll
    for (int nt = 0; nt < 4; ++nt) {
        float iv = init[w * 64 + nt * 16 + lr];
        #pragma unroll
        for (int e = 0; e < 4; ++e) xm[nt][e] = iv;
    }

    const int sq = w & 3;    // logits s-tile
    const int kh = w >> 2;   // logits K-half

    // per-lane A-fragment base pointers (one per nt-quarter of the wave's 64 rows)
    const short* aP0 = A16 + (w * 64 +      lr) * K_DIM + 8 * lg;
    const short* aP1 = A16 + (w * 64 + 16 + lr) * K_DIM + 8 * lg;
    const short* aP2 = A16 + (w * 64 + 32 + lr) * K_DIM + 8 * lg;
    const short* aP3 = A16 + (w * 64 + 48 + lr) * K_DIM + 8 * lg;

    // Ceff fragments resident (8 frags = 32 VGPR, step-invariant)
    const short* cP = Ceff16 + (sq * 16 + lr) * K_DIM + kh * 256 + 8 * lg;
    bf16x8 c0 = *(const bf16x8*)(cP +   0);
    bf16x8 c1 = *(const bf16x8*)(cP +  32);
    bf16x8 c2 = *(const bf16x8*)(cP +  64);
    bf16x8 c3 = *(const bf16x8*)(cP +  96);
    bf16x8 c4 = *(const bf16x8*)(cP + 128);
    bf16x8 c5 = *(const bf16x8*)(cP + 160);
    bf16x8 c6 = *(const bf16x8*)(cP + 192);
    bf16x8 c7 = *(const bf16x8*)(cP + 224);

    float llacc = 0.0f;

    // prime the ring with slices 0,1,2
    ISSUE(0); ISSUE(1); ISSUE(2);
    __syncthreads();   // full drain once (prologue only)

    for (int t = 0; t < T_LEN; ++t) {
        f32x4 acc0 = {0.f, 0.f, 0.f, 0.f};
        f32x4 acc1 = {0.f, 0.f, 0.f, 0.f};
        f32x4 acc2 = {0.f, 0.f, 0.f, 0.f};
        f32x4 acc3 = {0.f, 0.f, 0.f, 0.f};

        // ---- P2: update GEMM, 16 slices, ring 3 ahead, counted vmcnt
        ISSUE(3);  WAITV; CONS(0);
        ISSUE(4);  WAITV; CONS(1);
        ISSUE(5);  WAITV; CONS(2);
        ISSUE(6);  WAITV; CONS(3);
        ISSUE(7);  WAITV; CONS(4);
        ISSUE(8);  WAITV; CONS(5);
        ISSUE(9);  WAITV; CONS(6);
        ISSUE(10); WAITV; CONS(7);
        ISSUE(11); WAITV; CONS(8);
        ISSUE(12); WAITV; CONS(9);
        ISSUE(13); WAITV; CONS(10);
        ISSUE(14); WAITV; CONS(11);
        ISSUE(15); WAITV; CONS(12);
        ISSUE(0);  WAITV; CONS(13);   // wrap: next step's slices (same addresses)
        ISSUE(1);  WAITV; CONS(14);
        ISSUE(2);  WAITV;
        // strays issued after the last counted wait; consumed in P3
        int mytok[4];
        #pragma unroll
        for (int e = 0; e < 4; ++e) mytok[e] = tokS[4 * lg + e][t];
        float piv[4][4], pbv[4][4];
        #pragma unroll
        for (int nt = 0; nt < 4; ++nt) {
            int k = w * 64 + nt * 16 + lr;
            #pragma unroll
            for (int e = 0; e < 4; ++e) {
                piv[nt][e] = PI32[mytok[e] * K_DIM + k];
                pbv[nt][e] = PB32[mytok[e] * K_DIM + k];
            }
        }
        CONS(15);

        // ---- P1: logits partial GEMM (K-half kh), resident cb + LDS xa
        f32x4 lga = {0.f, 0.f, 0.f, 0.f};
        {
            bf16x8 x0 = *(const bf16x8*)&Xb[lr][kh * 256 +   0 + 8 * lg]; MFMA_(x0, c0, lga);
            bf16x8 x1 = *(const bf16x8*)&Xb[lr][kh * 256 +  32 + 8 * lg]; MFMA_(x1, c1, lga);
            bf16x8 x2 = *(const bf16x8*)&Xb[lr][kh * 256 +  64 + 8 * lg]; MFMA_(x2, c2, lga);
            bf16x8 x3 = *(const bf16x8*)&Xb[lr][kh * 256 +  96 + 8 * lg]; MFMA_(x3, c3, lga);
            bf16x8 x4 = *(const bf16x8*)&Xb[lr][kh * 256 + 128 + 8 * lg]; MFMA_(x4, c4, lga);
            bf16x8 x5 = *(const bf16x8*)&Xb[lr][kh * 256 + 160 + 8 * lg]; MFMA_(x5, c5, lga);
            bf16x8 x6 = *(const bf16x8*)&Xb[lr][kh * 256 + 192 + 8 * lg]; MFMA_(x6, c6, lga);
            bf16x8 x7 = *(const bf16x8*)&Xb[lr][kh * 256 + 224 + 8 * lg]; MFMA_(x7, c7, lga);
        }
        #pragma unroll
        for (int e = 0; e < 4; ++e)
            Lg[kh][4 * lg + e][sq * 16 + lr] = lga[e];

        LBAR;   // barrier1: Xb reads done, Lg visible (LDS-only -> lgkm drain suffices)

        // ---- P3: gating in fp32, rewrite Xb
        #pragma unroll
        for (int nt = 0; nt < 4; ++nt) {
            int k = w * 64 + nt * 16 + lr;
            #pragma unroll
            for (int e = 0; e < 4; ++e) {
                float a  = (nt == 0) ? acc0[e] : (nt == 1) ? acc1[e]
                         : (nt == 2) ? acc2[e] : acc3[e];
                float nx = xm[nt][e] + piv[nt][e] * (a - xm[nt][e]) + pbv[nt][e];
                xm[nt][e] = nx;
                Xb[4 * lg + e][k] = f2bf(nx);
            }
        }
        // waves 0..3: log-softmax + LL for 4 seqs each (16 lanes/seq, 4 logits/lane)
        if (w < 4) {
            int b = w * 4 + (l >> 4);
            int i = l & 15;
            float v[4];
            #pragma unroll
            for (int c = 0; c < 4; ++c)
                v[c] = Lg[0][b][i * 4 + c] + Lg[1][b][i * 4 + c];
            float m = fmaxf(fmaxf(v[0], v[1]), fmaxf(v[2], v[3]));
            m = fmaxf(m, __shfl_xor(m, 1));
            m = fmaxf(m, __shfl_xor(m, 2));
            m = fmaxf(m, __shfl_xor(m, 4));
            m = fmaxf(m, __shfl_xor(m, 8));
            float sum = expf(v[0] - m) + expf(v[1] - m) + expf(v[2] - m) + expf(v[3] - m);
            sum += __shfl_xor(sum, 1);
            sum += __shfl_xor(sum, 2);
            sum += __shfl_xor(sum, 4);
            sum += __shfl_xor(sum, 8);
            int tok = tokS[b][t];
            float sel = (i == (tok >> 2)) ? v[tok & 3] : 0.0f;
            sel += __shfl_xor(sel, 1);
            sel += __shfl_xor(sel, 2);
            sel += __shfl_xor(sel, 4);
            sel += __shfl_xor(sel, 8);
            llacc += sel - m - logf(sum);
        }
        LBAR;   // barrier2: new Xb visible, Lg consumed
    }

    if (w < 4 && (l & 15) == 0)
        out[b0 + w * 4 + (l >> 4)] = llacc;
}

extern "C" void kernel_launch(void* const* d_in, const int* in_sizes, int n_in,
                              void* d_out, int out_size, void* d_ws, size_t ws_size,
                              hipStream_t stream) {
    const float* A  = (const float*)d_in[0];   // (512,512)
    const float* B  = (const float*)d_in[1];   // (512,64)
    const float* C  = (const float*)d_in[2];   // (64,512)
    const float* Pp = (const float*)d_in[3];   // (64,512)
    const float* init = (const float*)d_in[4]; // (512,)
    const int* tokens = (const int*)d_in[5];   // (512,64)
    float* out = (float*)d_out;

    // workspace layout (needs 851,968 bytes)
    short* A16    = (short*)d_ws;                              // 512*512*2 = 524288
    short* Ceff16 = (short*)((char*)d_ws + 524288);            // 64*512*2  =  65536
    float* PI32   = (float*)((char*)d_ws + 589824);            // 64*512*4  = 131072
    float* PB32   = (float*)((char*)d_ws + 720896);            // 64*512*4  = 131072

    ssm_prep<<<256, 256, 0, stream>>>(A, B, C, Pp, A16, Ceff16, PI32, PB32);
    ssm_main<<<NWG, 512, 0, stream>>>(A16, Ceff16, PI32, PB32, init, tokens, out);
}

// Round 10
// 495.355 us; speedup vs baseline: 7.8689x; 2.0355x over previous
//
#include <hip/hip_runtime.h>

#define K_DIM 512
#define S_DIM 64
#define T_LEN 64
#define BW    16      // sequences per workgroup
#define NWG   32      // 32 workgroups x 16 seqs = 512

typedef float f32x4 __attribute__((ext_vector_type(4)));
typedef float f32x2 __attribute__((ext_vector_type(2)));
typedef short bf16x8 __attribute__((ext_vector_type(8)));

__device__ __forceinline__ short f2bf(float f) {
    unsigned u = __builtin_bit_cast(unsigned, f);
    u += 0x7fffu + ((u >> 16) & 1u);   // round-to-nearest-even
    return (short)(u >> 16);
}

// ---------------- pre-pass: bf16 A/Ceff + packed {pi, pi*Bt} pairs ----------------
__global__ void ssm_prep(const float* __restrict__ A, const float* __restrict__ B,
                         const float* __restrict__ C, const float* __restrict__ Pp,
                         short* __restrict__ A16, short* __restrict__ Ceff16,
                         f32x2* __restrict__ PPB) {
    int i = blockIdx.x * blockDim.x + threadIdx.x;
    int stride = gridDim.x * blockDim.x;
    for (int idx = i; idx < K_DIM * K_DIM; idx += stride)
        A16[idx] = f2bf(A[idx]);
    for (int idx = i; idx < S_DIM * K_DIM; idx += stride) {
        int s = idx >> 9;               // K_DIM == 512
        int k = idx & (K_DIM - 1);
        float p = 1.0f / (1.0f + expf(-Pp[idx]));
        Ceff16[idx] = f2bf(C[idx] * p);
        PPB[idx] = (f32x2){p, p * B[k * S_DIM + s]};   // {pi, pi*Bt[tok][k]}
    }
}

#define MFMA_(xa, fb, acc) acc = __builtin_amdgcn_mfma_f32_16x16x32_bf16(xa, fb, acc, 0, 0, 0)

// stream slice s (32-wide k-chunk, all 4 nt-quarters) into SSA temps: 16 VGPRs
#define LOADS4(s) \
    bf16x8 fa_##s = *(const bf16x8*)(aP0 + (s) * 32); \
    bf16x8 fb_##s = *(const bf16x8*)(aP1 + (s) * 32); \
    bf16x8 fc_##s = *(const bf16x8*)(aP2 + (s) * 32); \
    bf16x8 fd_##s = *(const bf16x8*)(aP3 + (s) * 32);

#define COMPS4(s) { \
    bf16x8 xa = *(const bf16x8*)&Xb[lr][(s) * 32 + 8 * lg]; \
    MFMA_(xa, fa_##s, acc0); MFMA_(xa, fb_##s, acc1); \
    MFMA_(xa, fc_##s, acc2); MFMA_(xa, fd_##s, acc3); }

// raw barrier: drain LDS ops only; wave-private vmem loads ride across
#define LBAR asm volatile("s_waitcnt lgkmcnt(0)\ns_barrier" ::: "memory")

// ---------------- main: 32 WGs x 512 threads (8 waves), 16 seqs/WG, 64 steps ----------------
__global__ __launch_bounds__(512) __attribute__((amdgpu_waves_per_eu(2, 2)))
void ssm_main(
    const short* __restrict__ A16,     // [K][K] bf16 row-major
    const short* __restrict__ Ceff16,  // [S][K] bf16
    const f32x2* __restrict__ PPB,     // [S][K] {pi, pi*Bt}
    const float* __restrict__ init,    // [K]
    const int*   __restrict__ tokens,  // [BSZ][T]
    float*       __restrict__ out)     // [BSZ]
{
    __shared__ short Xb[BW][520];           // 16.6 KB bf16 state
    __shared__ short Cb[S_DIM][520];        // 66.6 KB Ceff (step-invariant, staged once)
    __shared__ float Lg[2][BW][68];         //  8.7 KB logits partials (2 K-halves)
    __shared__ int   tokS[BW][T_LEN];       //  4.1 KB   (total ~96 KB -> 1 WG/CU)

    const int tid = threadIdx.x;
    const int w  = tid >> 6;     // wave 0..7, owns k-range [w*64, w*64+64)
    const int l  = tid & 63;
    const int lg = l >> 4;
    const int lr = l & 15;
    const int b0 = blockIdx.x * BW;

    for (int idx = tid; idx < BW * T_LEN; idx += 512) {
        int r = idx >> 6, t = idx & 63;
        tokS[r][t] = tokens[(b0 + r) * T_LEN + t];
    }
    for (int idx = tid; idx < BW * K_DIM; idx += 512) {
        int r = idx >> 9, k = idx & (K_DIM - 1);
        Xb[r][k] = f2bf(init[k]);
    }
    for (int idx = tid; idx < (S_DIM * K_DIM) / 8; idx += 512) {
        int r = idx >> 6, c8 = (idx & 63) * 8;
        *(bf16x8*)&Cb[r][c8] = *(const bf16x8*)(Ceff16 + r * K_DIM + c8);
    }
    // fp32 master state: xm[nt][e] = x[seq=4*lg+e][k = w*64 + nt*16 + lr]
    float xm[4][4];
    #pragma unroll
    for (int nt = 0; nt < 4; ++nt) {
        float iv = init[w * 64 + nt * 16 + lr];
        #pragma unroll
        for (int e = 0; e < 4; ++e) xm[nt][e] = iv;
    }

    const int sq = w & 3;    // logits s-tile
    const int kh = w >> 2;   // logits K-half

    // per-lane A-fragment bases (one per nt-quarter of the wave's 64 rows)
    const short* aP0 = A16 + (w * 64 +      lr) * K_DIM + 8 * lg;
    const short* aP1 = A16 + (w * 64 + 16 + lr) * K_DIM + 8 * lg;
    const short* aP2 = A16 + (w * 64 + 32 + lr) * K_DIM + 8 * lg;
    const short* aP3 = A16 + (w * 64 + 48 + lr) * K_DIM + 8 * lg;

    float llacc = 0.0f;
    __syncthreads();

    for (int t = 0; t < T_LEN; ++t) {
        int mytok[4];
        #pragma unroll
        for (int e = 0; e < 4; ++e) mytok[e] = tokS[4 * lg + e][t];

        // ---- prime 3 slices; their L2 latency hides under P1
        LOADS4(0) LOADS4(1) LOADS4(2)

        // ---- P1: logits partial GEMM (K-half kh), LDS operands
        f32x4 lga = {0.f, 0.f, 0.f, 0.f};
        #pragma unroll
        for (int i = 0; i < 8; ++i) {
            bf16x8 xa = *(const bf16x8*)&Xb[lr][kh * 256 + i * 32 + 8 * lg];
            bf16x8 cb = *(const bf16x8*)&Cb[sq * 16 + lr][kh * 256 + i * 32 + 8 * lg];
            MFMA_(xa, cb, lga);
        }
        #pragma unroll
        for (int e = 0; e < 4; ++e)
            Lg[kh][4 * lg + e][sq * 16 + lr] = lga[e];

        // ---- P2: update GEMM, depth-3 slice pipeline, pure VGPR streaming
        f32x4 acc0 = {0.f, 0.f, 0.f, 0.f};
        f32x4 acc1 = {0.f, 0.f, 0.f, 0.f};
        f32x4 acc2 = {0.f, 0.f, 0.f, 0.f};
        f32x4 acc3 = {0.f, 0.f, 0.f, 0.f};
        COMPS4(0)  LOADS4(3)
        COMPS4(1)  LOADS4(4)
        COMPS4(2)  LOADS4(5)
        COMPS4(3)  LOADS4(6)
        COMPS4(4)  LOADS4(7)
        COMPS4(5)  LOADS4(8)
        COMPS4(6)  LOADS4(9)
        COMPS4(7)  LOADS4(10)
        COMPS4(8)  LOADS4(11)
        COMPS4(9)  LOADS4(12)
        COMPS4(10) LOADS4(13)
        COMPS4(11) LOADS4(14)
        COMPS4(12) LOADS4(15)
        COMPS4(13)
        // gating gathers issued while 8 frags remain in flight (VGPR peak ~124)
        f32x2 ppv[4][4];
        #pragma unroll
        for (int nt = 0; nt < 4; ++nt) {
            int k = w * 64 + nt * 16 + lr;
            #pragma unroll
            for (int e = 0; e < 4; ++e)
                ppv[nt][e] = PPB[mytok[e] * K_DIM + k];
        }
        COMPS4(14)
        COMPS4(15)
        LBAR;   // barrier1: Xb reads done, Lg visible (LDS-only exchange)

        // ---- P3: gating in fp32, rewrite Xb
        #pragma unroll
        for (int nt = 0; nt < 4; ++nt) {
            int k = w * 64 + nt * 16 + lr;
            #pragma unroll
            for (int e = 0; e < 4; ++e) {
                float a  = (nt == 0) ? acc0[e] : (nt == 1) ? acc1[e]
                         : (nt == 2) ? acc2[e] : acc3[e];
                float nx = xm[nt][e] + ppv[nt][e][0] * (a - xm[nt][e]) + ppv[nt][e][1];
                xm[nt][e] = nx;
                Xb[4 * lg + e][k] = f2bf(nx);
            }
        }
        // waves 0..3: log-softmax + LL for 4 seqs each (16 lanes/seq, 4 logits/lane)
        if (w < 4) {
            int b = w * 4 + (l >> 4);
            int i = l & 15;
            float v[4];
            #pragma unroll
            for (int c = 0; c < 4; ++c)
                v[c] = Lg[0][b][i * 4 + c] + Lg[1][b][i * 4 + c];
            float m = fmaxf(fmaxf(v[0], v[1]), fmaxf(v[2], v[3]));
            m = fmaxf(m, __shfl_xor(m, 1));
            m = fmaxf(m, __shfl_xor(m, 2));
            m = fmaxf(m, __shfl_xor(m, 4));
            m = fmaxf(m, __shfl_xor(m, 8));
            float sum = expf(v[0] - m) + expf(v[1] - m) + expf(v[2] - m) + expf(v[3] - m);
            sum += __shfl_xor(sum, 1);
            sum += __shfl_xor(sum, 2);
            sum += __shfl_xor(sum, 4);
            sum += __shfl_xor(sum, 8);
            int tok = tokS[b][t];
            float sel = (i == (tok >> 2)) ? v[tok & 3] : 0.0f;
            sel += __shfl_xor(sel, 1);
            sel += __shfl_xor(sel, 2);
            sel += __shfl_xor(sel, 4);
            sel += __shfl_xor(sel, 8);
            llacc += sel - m - logf(sum);
        }
        LBAR;   // barrier2: new Xb visible, Lg consumed
    }

    if (w < 4 && (l & 15) == 0)
        out[b0 + w * 4 + (l >> 4)] = llacc;
}

extern "C" void kernel_launch(void* const* d_in, const int* in_sizes, int n_in,
                              void* d_out, int out_size, void* d_ws, size_t ws_size,
                              hipStream_t stream) {
    const float* A  = (const float*)d_in[0];   // (512,512)
    const float* B  = (const float*)d_in[1];   // (512,64)
    const float* C  = (const float*)d_in[2];   // (64,512)
    const float* Pp = (const float*)d_in[3];   // (64,512)
    const float* init = (const float*)d_in[4]; // (512,)
    const int* tokens = (const int*)d_in[5];   // (512,64)
    float* out = (float*)d_out;

    // workspace layout (needs 851,968 bytes)
    short* A16    = (short*)d_ws;                              // 512*512*2 = 524288
    short* Ceff16 = (short*)((char*)d_ws + 524288);            // 64*512*2  =  65536
    f32x2* PPB    = (f32x2*)((char*)d_ws + 589824);            // 64*512*8  = 262144

    ssm_prep<<<256, 256, 0, stream>>>(A, B, C, Pp, A16, Ceff16, PPB);
    ssm_main<<<NWG, 512, 0, stream>>>(A16, Ceff16, PPB, init, tokens, out);
}